// Round 21
// baseline (102.881 us; speedup 1.0000x reference)
//
#include <hip/hip_runtime.h>

#define NDIM 128
#define NWPART 128    // partition workgroups
#define MAXBKT 1024   // max dst buckets (64 nodes each)

typedef __attribute__((ext_vector_type(8))) short s8v;   // 8 bf16 in 4 VGPRs
typedef __attribute__((ext_vector_type(4))) float f4v;   // MFMA accumulator
typedef __attribute__((ext_vector_type(2))) float f2v;   // cvt_pk result

__device__ inline unsigned short f2bf_rne(float x) {
    unsigned u = __float_as_uint(x);
    unsigned r = u + 0x7FFFu + ((u >> 16) & 1u);
    return (unsigned short)(r >> 16);
}
__device__ inline float bf2f(unsigned short b) {
    return __uint_as_float(((unsigned)b) << 16);
}

// ================= K1: fused weight-convert + proj/hb + part1 histogram ========
__global__ __launch_bounds__(256) void k_front(const float* __restrict__ h,
                                               const float* __restrict__ Wa1,
                                               const float* __restrict__ Wa2,
                                               const float* __restrict__ Wa3,
                                               float* __restrict__ proj,
                                               unsigned short* __restrict__ hb,
                                               const float* __restrict__ w0,
                                               const float* __restrict__ w1,
                                               const float* __restrict__ w2,
                                               const float* __restrict__ w3,
                                               const float* __restrict__ w4,
                                               const float* __restrict__ w5,
                                               unsigned short* __restrict__ wtout,
                                               const int* __restrict__ dst,
                                               int* __restrict__ hist,
                                               int N, int E, int nbkt)
{
    __shared__ int lh[MAXBKT];
    int tid = threadIdx.x;
    int nbProj = (N + 15) >> 4;
    int bid = blockIdx.x;

    if (bid < 384) {
        const float* srcs[6] = {w0, w1, w2, w3, w4, w5};
        int mat = bid >> 6;
        int idx = (bid & 63) * 256 + tid;    // 0..16383
        int j    = idx & 7;
        int lane = (idx >> 3) & 63;
        int ks   = (idx >> 9) & 3;
        int ct   = idx >> 11;
        int col  = ct * 16 + (lane & 15);
        int k    = ks * 32 + (lane >> 4) * 8 + j;
        wtout[(size_t)mat * 16384 + idx] = f2bf_rne(srcs[mat][k * 128 + col]);
        return;
    }
    bid -= 384;
    if (bid < nbProj) {
        int l = tid & 15;
        int n = bid * 16 + (tid >> 4);
        if (n >= N) return;
        int o = l * 8;
        float4 w1s0 = *(const float4*)(Wa1 + o),       w1s1 = *(const float4*)(Wa1 + o + 4);
        float4 w1d0 = *(const float4*)(Wa1 + 128 + o), w1d1 = *(const float4*)(Wa1 + 132 + o);
        float4 w2s0 = *(const float4*)(Wa2 + o),       w2s1 = *(const float4*)(Wa2 + o + 4);
        float4 w2d0 = *(const float4*)(Wa2 + 128 + o), w2d1 = *(const float4*)(Wa2 + 132 + o);
        float4 w3s0 = *(const float4*)(Wa3 + o),       w3s1 = *(const float4*)(Wa3 + o + 4);
        float4 w3d0 = *(const float4*)(Wa3 + 128 + o), w3d1 = *(const float4*)(Wa3 + 132 + o);
        float4 x0 = *(const float4*)(h + (size_t)n * NDIM + o);
        float4 x1 = *(const float4*)(h + (size_t)n * NDIM + o + 4);
        {
            s8v hv;
            hv[0] = (short)f2bf_rne(x0.x); hv[1] = (short)f2bf_rne(x0.y);
            hv[2] = (short)f2bf_rne(x0.z); hv[3] = (short)f2bf_rne(x0.w);
            hv[4] = (short)f2bf_rne(x1.x); hv[5] = (short)f2bf_rne(x1.y);
            hv[6] = (short)f2bf_rne(x1.z); hv[7] = (short)f2bf_rne(x1.w);
            *(s8v*)(hb + (size_t)n * NDIM + o) = hv;
        }
        float s1 = x0.x*w1s0.x + x0.y*w1s0.y + x0.z*w1s0.z + x0.w*w1s0.w
                 + x1.x*w1s1.x + x1.y*w1s1.y + x1.z*w1s1.z + x1.w*w1s1.w;
        float s2 = x0.x*w2s0.x + x0.y*w2s0.y + x0.z*w2s0.z + x0.w*w2s0.w
                 + x1.x*w2s1.x + x1.y*w2s1.y + x1.z*w2s1.z + x1.w*w2s1.w;
        float s3 = x0.x*w3s0.x + x0.y*w3s0.y + x0.z*w3s0.z + x0.w*w3s0.w
                 + x1.x*w3s1.x + x1.y*w3s1.y + x1.z*w3s1.z + x1.w*w3s1.w;
        float d1 = x0.x*w1d0.x + x0.y*w1d0.y + x0.z*w1d0.z + x0.w*w1d0.w
                 + x1.x*w1d1.x + x1.y*w1d1.y + x1.z*w1d1.z + x1.w*w1d1.w;
        float d2 = x0.x*w2d0.x + x0.y*w2d0.y + x0.z*w2d0.z + x0.w*w2d0.w
                 + x1.x*w2d1.x + x1.y*w2d1.y + x1.z*w2d1.z + x1.w*w2d1.w;
        float d3 = x0.x*w3d0.x + x0.y*w3d0.y + x0.z*w3d0.z + x0.w*w3d0.w
                 + x1.x*w3d1.x + x1.y*w3d1.y + x1.z*w3d1.z + x1.w*w3d1.w;
#pragma unroll
        for (int m = 1; m < 16; m <<= 1) {
            s1 += __shfl_xor(s1, m);
            s2 += __shfl_xor(s2, m);
            s3 += __shfl_xor(s3, m);
            d1 += __shfl_xor(d1, m);
            d2 += __shfl_xor(d2, m);
            d3 += __shfl_xor(d3, m);
        }
        if (l == 0) {
            *(float4*)(proj + (size_t)n * 8)     = make_float4(s1, s2, s3, 0.f);
            *(float4*)(proj + (size_t)n * 8 + 4) = make_float4(d1, d2, d3, 0.f);
        }
        return;
    }
    bid -= nbProj;
    {
        int w = bid, NW = NWPART;
        for (int i = tid; i < nbkt; i += 256) lh[i] = 0;
        __syncthreads();
        int per = (E + NW - 1) / NW;
        int e0 = w * per, e1 = min(E, e0 + per);
        for (int e = e0 + tid; e < e1; e += 256)
            atomicAdd(&lh[dst[e] >> 6], 1);
        __syncthreads();
        for (int b = tid; b < nbkt; b += 256)
            hist[b * NW + w] = lh[b];
    }
}

// ---------------- partition scan, parallelized
__global__ __launch_bounds__(NWPART) void k_pscan_a(int* __restrict__ hist,
                                                    int* __restrict__ tot)
{
    __shared__ int s[NWPART];
    int b = blockIdx.x, t = threadIdx.x;
    int v = hist[b * NWPART + t];
    s[t] = v;
    __syncthreads();
    for (int d = 1; d < NWPART; d <<= 1) {
        int u = (t >= d) ? s[t - d] : 0;
        __syncthreads();
        s[t] += u;
        __syncthreads();
    }
    hist[b * NWPART + t] = s[t] - v;
    if (t == NWPART - 1) tot[b] = s[NWPART - 1];
}

__global__ __launch_bounds__(MAXBKT) void k_pscan_b(const int* __restrict__ tot,
                                                    int* __restrict__ bbase,
                                                    int E, int nbkt)
{
    __shared__ int s[MAXBKT];
    int b = threadIdx.x;
    int v = (b < nbkt) ? tot[b] : 0;
    s[b] = v;
    __syncthreads();
    for (int d = 1; d < MAXBKT; d <<= 1) {
        int u = (b >= d) ? s[b - d] : 0;
        __syncthreads();
        s[b] += u;
        __syncthreads();
    }
    if (b < nbkt) bbase[b] = s[b] - v;
    if (b == nbkt - 1) bbase[nbkt] = E;
}

// ======== single-plane bf16 GEMM helpers (BM=64, 8 waves = 2rw x 4cw) ========

__device__ inline void g_pass_global(const unsigned short* __restrict__ A, int N, int row0,
                                     int ln, int g, int lane, int cw,
                                     const unsigned short* __restrict__ wf, f4v acc[2][2])
{
#pragma unroll
    for (int ks = 0; ks < 4; ++ks) {
        s8v a[2];
#pragma unroll
        for (int fr = 0; fr < 2; ++fr) {
            int rA = min(row0 + fr * 16 + ln, N - 1);
            a[fr] = *(const s8v*)(A + (size_t)rA * 128 + ks * 32 + g * 8);
        }
#pragma unroll
        for (int ct2 = 0; ct2 < 2; ++ct2) {
            int ct = cw * 2 + ct2;
            s8v wv = *(const s8v*)(wf + ((((ct << 2) + ks) * 64) + lane) * 8);
#pragma unroll
            for (int fr = 0; fr < 2; ++fr)
                acc[fr][ct2] = __builtin_amdgcn_mfma_f32_16x16x32_bf16(a[fr], wv, acc[fr][ct2], 0, 0, 0);
        }
    }
}

__device__ inline void g_pass_lds(const unsigned short* __restrict__ act,
                                  int rw, int ln, int g, int lane, int cw,
                                  const unsigned short* __restrict__ wf, f4v acc[2][2])
{
#pragma unroll
    for (int ks = 0; ks < 4; ++ks) {
        s8v a[2];
#pragma unroll
        for (int fr = 0; fr < 2; ++fr) {
            int rl = rw * 32 + fr * 16 + ln;
            a[fr] = *(const s8v*)(&act[(rl * 128 + ks * 32 + g * 8) ^ ((ln & 7) << 3)]);
        }
#pragma unroll
        for (int ct2 = 0; ct2 < 2; ++ct2) {
            int ct = cw * 2 + ct2;
            s8v wv = *(const s8v*)(wf + ((((ct << 2) + ks) * 64) + lane) * 8);
#pragma unroll
            for (int fr = 0; fr < 2; ++fr)
                acc[fr][ct2] = __builtin_amdgcn_mfma_f32_16x16x32_bf16(a[fr], wv, acc[fr][ct2], 0, 0, 0);
        }
    }
}

__device__ inline void write_act(f4v acc[2][2], const float* __restrict__ bias,
                                 unsigned short* __restrict__ act,
                                 int rw, int cw, int ln, int g)
{
#pragma unroll
    for (int ct2 = 0; ct2 < 2; ++ct2) {
        int col = (cw * 2 + ct2) * 16 + ln;
        float bv = bias[col];
#pragma unroll
        for (int fr = 0; fr < 2; ++fr) {
#pragma unroll
            for (int q = 0; q < 4; ++q) {
                int rl = rw * 32 + fr * 16 + g * 4 + q;
                float o = fmaxf(acc[fr][ct2][q] + bv, 0.f);
                act[(rl * 128 + col) ^ ((rl & 7) << 3)] = f2bf_rne(o);
                acc[fr][ct2][q] = 0.f;
            }
        }
    }
}

// ================= K4: fused part2 scatter + 3-layer message MLP (fp8 msg out)
__global__ __launch_bounds__(512) void k_mid(const int* __restrict__ src,
                                             const int* __restrict__ dst,
                                             const int* __restrict__ hist,
                                             const int* __restrict__ bbase,
                                             unsigned* __restrict__ ebuf,
                                             int E, int nbkt,
                                             const unsigned short* __restrict__ hb,
                                             const unsigned short* __restrict__ w1,
                                             const unsigned short* __restrict__ w2,
                                             const unsigned short* __restrict__ w3,
                                             const float* __restrict__ b1,
                                             const float* __restrict__ b2,
                                             const float* __restrict__ b3,
                                             unsigned char* __restrict__ msg, int N)
{
    __shared__ int cur[MAXBKT];
    __shared__ unsigned short act0[8192];
    __shared__ unsigned short act1[8192];
    int tid = threadIdx.x;

    if (blockIdx.x < NWPART) {
        int w = blockIdx.x, NW = NWPART;
        for (int i = tid; i < nbkt; i += 512)
            cur[i] = hist[i * NW + w] + bbase[i];
        __syncthreads();
        int per = (E + NW - 1) / NW;
        int e0 = w * per, e1 = min(E, e0 + per);
        for (int e = e0 + tid; e < e1; e += 512) {
            int d = dst[e], b = d >> 6;
            int pos = atomicAdd(&cur[b], 1);
            ebuf[pos] = ((unsigned)src[e] << 7) | (unsigned)(d & 63);
        }
        return;
    }
    int mb   = blockIdx.x - NWPART;
    int lane = tid & 63;
    int wid  = tid >> 6;
    int rw   = wid >> 2;
    int cw   = wid & 3;
    int ln   = lane & 15;
    int g    = lane >> 4;
    int row0 = mb * 64 + rw * 32;

    f4v acc[2][2] = {};
    g_pass_global(hb, N, row0, ln, g, lane, cw, w1, acc);
    write_act(acc, b1, act0, rw, cw, ln, g);
    __syncthreads();
    g_pass_lds(act0, rw, ln, g, lane, cw, w2, acc);
    write_act(acc, b2, act1, rw, cw, ln, g);
    __syncthreads();
    g_pass_lds(act1, rw, ln, g, lane, cw, w3, acc);
    write_act(acc, b3, act0, rw, cw, ln, g);
    __syncthreads();
    // coalesced fp8 copyout (HW cvt_pk encode, RNE)
#pragma unroll
    for (int i = 0; i < 2; ++i) {
        int id  = tid + 512 * i;
        int row = id >> 4;
        int c8  = (id & 15) * 8;
        int grow = mb * 64 + row;
        if (grow < N) {
            s8v v = *(const s8v*)(&act0[(row * 128 + c8) ^ ((row & 7) << 3)]);
            unsigned lo = 0, hi = 0;
            lo = __builtin_amdgcn_cvt_pk_fp8_f32(bf2f((unsigned short)v[0]),
                                                 bf2f((unsigned short)v[1]), lo, false);
            lo = __builtin_amdgcn_cvt_pk_fp8_f32(bf2f((unsigned short)v[2]),
                                                 bf2f((unsigned short)v[3]), lo, true);
            hi = __builtin_amdgcn_cvt_pk_fp8_f32(bf2f((unsigned short)v[4]),
                                                 bf2f((unsigned short)v[5]), hi, false);
            hi = __builtin_amdgcn_cvt_pk_fp8_f32(bf2f((unsigned short)v[6]),
                                                 bf2f((unsigned short)v[7]), hi, true);
            unsigned long long packed = ((unsigned long long)hi << 32) | lo;
            *(unsigned long long*)(msg + (size_t)grow * 128 + c8) = packed;
        }
    }
}

// decode+accumulate 8 fp8 (one 8B fragment) with weight w, HW cvt_pk
__device__ inline void acc8_fp8(float* acc, unsigned long long raw, float w)
{
    unsigned lo = (unsigned)raw, hi = (unsigned)(raw >> 32);
    f2v p0 = __builtin_amdgcn_cvt_pk_f32_fp8(lo, false);
    f2v p1 = __builtin_amdgcn_cvt_pk_f32_fp8(lo, true);
    f2v p2 = __builtin_amdgcn_cvt_pk_f32_fp8(hi, false);
    f2v p3 = __builtin_amdgcn_cvt_pk_f32_fp8(hi, true);
    acc[0] += w * p0.x; acc[1] += w * p0.y;
    acc[2] += w * p1.x; acc[3] += w * p1.y;
    acc[4] += w * p2.x; acc[5] += w * p2.y;
    acc[6] += w * p3.x; acc[7] += w * p3.y;
}

// ================= K5: fused local-CSR + aggregation (fp8 HW-cvt, 2-deep) + head
__global__ __launch_bounds__(512) void k_tail(const unsigned short* __restrict__ hb,
                                              const unsigned char* __restrict__ msgb,
                                              const float* __restrict__ proj,
                                              const int* __restrict__ bbase,
                                              const unsigned* __restrict__ ebuf,
                                              const float* __restrict__ ba1,
                                              const float* __restrict__ ba2,
                                              const float* __restrict__ ba3,
                                              const unsigned short* __restrict__ wc1a,
                                              const unsigned short* __restrict__ wc1b,
                                              const unsigned short* __restrict__ wc2,
                                              const float* __restrict__ bc1,
                                              const float* __restrict__ bc2,
                                              float* __restrict__ out, int N)
{
    __shared__ unsigned short hn[8192];
    __shared__ unsigned short act0[8192];
    __shared__ int lperm[1536];
    __shared__ int lcnt[64];
    __shared__ int lsc[64];
    __shared__ int loffs[65];
    __shared__ int lcur[64];
    int tid  = threadIdx.x;
    int lane = tid & 63;
    int l    = lane & 15;
    int grp  = lane >> 4;      // 0..3 within wave
    int wv   = tid >> 6;       // 0..7
    int r0   = blockIdx.x * 64;
    float b1 = ba1[0], b2 = ba2[0], b3 = ba3[0];

    // ---- prologue: local CSR for this bucket (64 dst nodes)
    int be0 = bbase[blockIdx.x], be1 = bbase[blockIdx.x + 1];
    if (tid < 64) lcnt[tid] = 0;
    __syncthreads();
    for (int e = be0 + tid; e < be1; e += 512)
        atomicAdd(&lcnt[ebuf[e] & 63], 1);
    __syncthreads();
    if (tid < 64) lsc[tid] = lcnt[tid];
    __syncthreads();
    for (int d = 1; d < 64; d <<= 1) {
        int u = (tid < 64 && tid >= d) ? lsc[tid - d] : 0;
        __syncthreads();
        if (tid < 64) lsc[tid] += u;
        __syncthreads();
    }
    if (tid < 64) {
        int excl = lsc[tid] - lcnt[tid];
        loffs[tid] = excl;
        lcur[tid]  = excl;
        if (tid == 63) loffs[64] = lsc[63];
    }
    __syncthreads();
    for (int e = be0 + tid; e < be1; e += 512) {
        unsigned r = ebuf[e];
        int p = atomicAdd(&lcur[r & 63], 1);
        if (p < 1536) lperm[p] = (int)(r >> 7);
    }
    __syncthreads();

    // ---- Phase A: aggregation into hn LDS (fp8 rows, HW decode, 2-deep gather)
    for (int rnd = 0; rnd < 2; ++rnd) {
        int rl = rnd * 32 + wv * 4 + grp;
        int n  = r0 + rl;
        bool alive = (n < N);
        int o0 = loffs[rl], o1 = loffs[rl + 1];
        float dd1 = 0.f, dd2 = 0.f, dd3 = 0.f;
        if (alive) {
            dd1 = proj[(size_t)n * 8 + 4];
            dd2 = proj[(size_t)n * 8 + 5];
            dd3 = proj[(size_t)n * 8 + 6];
        }
        int deg = o1 - o0;

        int   m0 = min(deg, 16);
        int   sc = 0;
        float a1c = 0.f, a2c = 0.f, a3c = 0.f;
        if (l < m0) {
            sc = lperm[o0 + l];
            float4 sp = *(const float4*)(proj + (size_t)sc * 8);
            a1c = __expf(fmaxf(sp.x + dd1 + b1, 0.f));
            a2c = __expf(fmaxf(sp.y + dd2 + b2, 0.f));
            a3c = __expf(fmaxf(sp.z + dd3 + b3, 0.f));
        }
        float s1 = a1c, s2 = a2c, s3 = a3c;
        for (int i = o0 + 16 + l; i < o1; i += 16) {
            int s = lperm[i];
            float4 sp = *(const float4*)(proj + (size_t)s * 8);
            s1 += __expf(fmaxf(sp.x + dd1 + b1, 0.f));
            s2 += __expf(fmaxf(sp.y + dd2 + b2, 0.f));
            s3 += __expf(fmaxf(sp.z + dd3 + b3, 0.f));
        }
#pragma unroll
        for (int m = 1; m < 16; m <<= 1) {
            s1 += __shfl_xor(s1, m);
            s2 += __shfl_xor(s2, m);
            s3 += __shfl_xor(s3, m);
        }
        float r1 = 1.f / s1, r2 = 1.f / s2, r3 = 1.f / s3;

        float acc[8] = {};
        int gbase = grp << 4;
        {
            float wvv = (a1c * r1 + a2c * r2 + a3c * r3) * (1.f / 3.f);
            int j = 0;
            for (; j + 2 <= m0; j += 2) {
                int   sA = __shfl(sc, gbase + j);
                int   sB = __shfl(sc, gbase + j + 1);
                float wA = __shfl(wvv, gbase + j);
                float wB = __shfl(wvv, gbase + j + 1);
                unsigned long long rA = *(const unsigned long long*)(msgb + (size_t)sA * 128 + l * 8);
                unsigned long long rB = *(const unsigned long long*)(msgb + (size_t)sB * 128 + l * 8);
                acc8_fp8(acc, rA, wA);
                acc8_fp8(acc, rB, wB);
            }
            if (j < m0) {
                int   s = __shfl(sc, gbase + j);
                float w = __shfl(wvv, gbase + j);
                unsigned long long raw = *(const unsigned long long*)(msgb + (size_t)s * 128 + l * 8);
                acc8_fp8(acc, raw, w);
            }
        }
        for (int base = o0 + 16; base < o1; base += 16) {
            int m  = min(16, o1 - base);
            int sv = 0;
            float wvv = 0.f;
            if (l < m) {
                sv = lperm[base + l];
                float4 sp = *(const float4*)(proj + (size_t)sv * 8);
                float a1 = __expf(fmaxf(sp.x + dd1 + b1, 0.f));
                float a2 = __expf(fmaxf(sp.y + dd2 + b2, 0.f));
                float a3 = __expf(fmaxf(sp.z + dd3 + b3, 0.f));
                wvv = (a1 * r1 + a2 * r2 + a3 * r3) * (1.f / 3.f);
            }
            int j = 0;
            for (; j + 2 <= m; j += 2) {
                int   sA = __shfl(sv, gbase + j);
                int   sB = __shfl(sv, gbase + j + 1);
                float wA = __shfl(wvv, gbase + j);
                float wB = __shfl(wvv, gbase + j + 1);
                unsigned long long rA = *(const unsigned long long*)(msgb + (size_t)sA * 128 + l * 8);
                unsigned long long rB = *(const unsigned long long*)(msgb + (size_t)sB * 128 + l * 8);
                acc8_fp8(acc, rA, wA);
                acc8_fp8(acc, rB, wB);
            }
            if (j < m) {
                int   s = __shfl(sv, gbase + j);
                float w = __shfl(wvv, gbase + j);
                unsigned long long raw = *(const unsigned long long*)(msgb + (size_t)s * 128 + l * 8);
                acc8_fp8(acc, raw, w);
            }
        }
        float inv = (alive && deg > 0) ? 1.f / (float)deg : 0.f;
        s8v hv;
#pragma unroll
        for (int k = 0; k < 8; ++k)
            hv[k] = (short)f2bf_rne(acc[k] * inv);
        *(s8v*)(&hn[(rl * 128 + l * 8) ^ ((rl & 7) << 3)]) = hv;
    }
    __syncthreads();

    // ---- Phase B: c1 (hb global + hn LDS) -> act0 -> c2 -> out
    int wid  = tid >> 6;
    int rw   = wid >> 2;
    int cw   = wid & 3;
    int ln   = lane & 15;
    int g    = lane >> 4;
    int row0 = r0 + rw * 32;

    f4v acc2[2][2] = {};
    g_pass_global(hb, N, row0, ln, g, lane, cw, wc1a, acc2);
    g_pass_lds(hn, rw, ln, g, lane, cw, wc1b, acc2);
    write_act(acc2, bc1, act0, rw, cw, ln, g);
    __syncthreads();
    g_pass_lds(act0, rw, ln, g, lane, cw, wc2, acc2);
#pragma unroll
    for (int ct2 = 0; ct2 < 2; ++ct2) {
        int col = (cw * 2 + ct2) * 16 + ln;
        float bv = bc2[col];
#pragma unroll
        for (int fr = 0; fr < 2; ++fr) {
#pragma unroll
            for (int q = 0; q < 4; ++q) {
                int orow = row0 + fr * 16 + g * 4 + q;
                if (orow < N)
                    out[(size_t)orow * 128 + col] = acc2[fr][ct2][q] + bv;
            }
        }
    }
}

extern "C" void kernel_launch(void* const* d_in, const int* in_sizes, int n_in,
                              void* d_out, int out_size, void* d_ws, size_t ws_size,
                              hipStream_t stream)
{
    const float* h   = (const float*)d_in[0];
    const int*   src = (const int*)d_in[1];
    const int*   dst = (const int*)d_in[2];
    const float* Wm1 = (const float*)d_in[3];
    const float* bm1 = (const float*)d_in[4];
    const float* Wm2 = (const float*)d_in[5];
    const float* bm2 = (const float*)d_in[6];
    const float* Wm3 = (const float*)d_in[7];
    const float* bm3 = (const float*)d_in[8];
    const float* Wa1 = (const float*)d_in[9];
    const float* ba1 = (const float*)d_in[10];
    const float* Wa2 = (const float*)d_in[11];
    const float* ba2 = (const float*)d_in[12];
    const float* Wa3 = (const float*)d_in[13];
    const float* ba3 = (const float*)d_in[14];
    const float* Wc1 = (const float*)d_in[15];
    const float* bc1 = (const float*)d_in[16];
    const float* Wc2 = (const float*)d_in[17];
    const float* bc2 = (const float*)d_in[18];

    const int N = in_sizes[0] / NDIM;
    const int E = in_sizes[1];
    const int nbkt = (N + 63) >> 6;            // 64-node buckets == k_tail tiles
    float* out = (float*)d_out;

    // workspace layout
    unsigned short* wt  = (unsigned short*)d_ws;                 // 6*16384 ushorts (192 KB)
    unsigned short* hb  = wt + 6 * 16384;                        // N*128 bf16 (h cast)
    unsigned char* mb2  = (unsigned char*)(hb + (size_t)N * NDIM); // N*128 fp8 (msg)
    float* proj = (float*)(mb2 + (size_t)N * NDIM);              // N*8
    int* hist   = (int*)(proj + (size_t)N * 8);                  // nbkt*NWPART
    int* bbase  = hist + MAXBKT * NWPART;                        // nbkt+1
    int* btot   = bbase + MAXBKT + 1;                            // nbkt
    unsigned* ebuf = (unsigned*)(btot + MAXBKT);                 // E

    const unsigned short* wt_m1  = wt;
    const unsigned short* wt_m2  = wt + 1 * 16384;
    const unsigned short* wt_m3  = wt + 2 * 16384;
    const unsigned short* wt_c1a = wt + 3 * 16384;
    const unsigned short* wt_c1b = wt + 4 * 16384;
    const unsigned short* wt_c2  = wt + 5 * 16384;

    int nbProj = (N + 15) / 16;
    int gb64   = nbkt;

    // K1: cvt_w (384) + proj (nbProj) + part1 (NWPART)
    k_front<<<384 + nbProj + NWPART, 256, 0, stream>>>(
        h, Wa1, Wa2, Wa3, proj, hb,
        Wm1, Wm2, Wm3, Wc1, Wc1 + 128 * 128, Wc2, wt,
        dst, hist, N, E, nbkt);

    // K2/K3: partition scans
    k_pscan_a<<<nbkt, NWPART, 0, stream>>>(hist, btot);
    k_pscan_b<<<1, MAXBKT, 0, stream>>>(btot, bbase, E, nbkt);

    // K4: part2 (NWPART) + mlp3 (gb64), fp8 msg out
    k_mid<<<NWPART + gb64, 512, 0, stream>>>(
        src, dst, hist, bbase, ebuf, E, nbkt,
        hb, wt_m1, wt_m2, wt_m3, bm1, bm2, bm3, mb2, N);

    // K5: fused local-CSR + fp8-gather aggregation + head
    k_tail<<<gb64, 512, 0, stream>>>(
        hb, mb2, proj, bbase, ebuf, ba1, ba2, ba3,
        wt_c1a, wt_c1b, wt_c2, bc1, bc2, out, N);
}

// Round 22
// 95.844 us; speedup vs baseline: 1.0734x; 1.0734x over previous
//
#include <hip/hip_runtime.h>

#define NDIM 128
#define NWPART 128    // partition workgroups
#define MAXBKT 1024   // max dst buckets (64 nodes each)

typedef __attribute__((ext_vector_type(8))) short s8v;   // 8 bf16 in 4 VGPRs
typedef __attribute__((ext_vector_type(4))) float f4v;   // MFMA accumulator

__device__ inline unsigned short f2bf_rne(float x) {
    unsigned u = __float_as_uint(x);
    unsigned r = u + 0x7FFFu + ((u >> 16) & 1u);
    return (unsigned short)(r >> 16);
}
__device__ inline float bf2f(unsigned short b) {
    return __uint_as_float(((unsigned)b) << 16);
}
// e4m3 (OCP, non-negative post-relu values) via bit math:
__device__ inline float fp8d(unsigned b) {
    return __uint_as_float((b & 0x7Fu) << 20) * 0x1p120f;
}
__device__ inline unsigned fp8e(float x) {
    unsigned bits = __float_as_uint(x * 0x1p-120f);
    unsigned r = bits + 0x7FFFFu + ((bits >> 20) & 1u);
    return (r >> 20) & 0x7Fu;
}

// ================= K1: fused weight-convert + proj/hb + part1 histogram ========
__global__ __launch_bounds__(256) void k_front(const float* __restrict__ h,
                                               const float* __restrict__ Wa1,
                                               const float* __restrict__ Wa2,
                                               const float* __restrict__ Wa3,
                                               float* __restrict__ proj,
                                               unsigned short* __restrict__ hb,
                                               const float* __restrict__ w0,
                                               const float* __restrict__ w1,
                                               const float* __restrict__ w2,
                                               const float* __restrict__ w3,
                                               const float* __restrict__ w4,
                                               const float* __restrict__ w5,
                                               unsigned short* __restrict__ wtout,
                                               const int* __restrict__ dst,
                                               int* __restrict__ hist,
                                               int N, int E, int nbkt)
{
    __shared__ int lh[MAXBKT];
    int tid = threadIdx.x;
    int nbProj = (N + 15) >> 4;
    int bid = blockIdx.x;

    if (bid < 384) {
        const float* srcs[6] = {w0, w1, w2, w3, w4, w5};
        int mat = bid >> 6;
        int idx = (bid & 63) * 256 + tid;    // 0..16383
        int j    = idx & 7;
        int lane = (idx >> 3) & 63;
        int ks   = (idx >> 9) & 3;
        int ct   = idx >> 11;
        int col  = ct * 16 + (lane & 15);
        int k    = ks * 32 + (lane >> 4) * 8 + j;
        wtout[(size_t)mat * 16384 + idx] = f2bf_rne(srcs[mat][k * 128 + col]);
        return;
    }
    bid -= 384;
    if (bid < nbProj) {
        int l = tid & 15;
        int n = bid * 16 + (tid >> 4);
        if (n >= N) return;
        int o = l * 8;
        float4 w1s0 = *(const float4*)(Wa1 + o),       w1s1 = *(const float4*)(Wa1 + o + 4);
        float4 w1d0 = *(const float4*)(Wa1 + 128 + o), w1d1 = *(const float4*)(Wa1 + 132 + o);
        float4 w2s0 = *(const float4*)(Wa2 + o),       w2s1 = *(const float4*)(Wa2 + o + 4);
        float4 w2d0 = *(const float4*)(Wa2 + 128 + o), w2d1 = *(const float4*)(Wa2 + 132 + o);
        float4 w3s0 = *(const float4*)(Wa3 + o),       w3s1 = *(const float4*)(Wa3 + o + 4);
        float4 w3d0 = *(const float4*)(Wa3 + 128 + o), w3d1 = *(const float4*)(Wa3 + 132 + o);
        float4 x0 = *(const float4*)(h + (size_t)n * NDIM + o);
        float4 x1 = *(const float4*)(h + (size_t)n * NDIM + o + 4);
        {
            s8v hv;
            hv[0] = (short)f2bf_rne(x0.x); hv[1] = (short)f2bf_rne(x0.y);
            hv[2] = (short)f2bf_rne(x0.z); hv[3] = (short)f2bf_rne(x0.w);
            hv[4] = (short)f2bf_rne(x1.x); hv[5] = (short)f2bf_rne(x1.y);
            hv[6] = (short)f2bf_rne(x1.z); hv[7] = (short)f2bf_rne(x1.w);
            *(s8v*)(hb + (size_t)n * NDIM + o) = hv;
        }
        float s1 = x0.x*w1s0.x + x0.y*w1s0.y + x0.z*w1s0.z + x0.w*w1s0.w
                 + x1.x*w1s1.x + x1.y*w1s1.y + x1.z*w1s1.z + x1.w*w1s1.w;
        float s2 = x0.x*w2s0.x + x0.y*w2s0.y + x0.z*w2s0.z + x0.w*w2s0.w
                 + x1.x*w2s1.x + x1.y*w2s1.y + x1.z*w2s1.z + x1.w*w2s1.w;
        float s3 = x0.x*w3s0.x + x0.y*w3s0.y + x0.z*w3s0.z + x0.w*w3s0.w
                 + x1.x*w3s1.x + x1.y*w3s1.y + x1.z*w3s1.z + x1.w*w3s1.w;
        float d1 = x0.x*w1d0.x + x0.y*w1d0.y + x0.z*w1d0.z + x0.w*w1d0.w
                 + x1.x*w1d1.x + x1.y*w1d1.y + x1.z*w1d1.z + x1.w*w1d1.w;
        float d2 = x0.x*w2d0.x + x0.y*w2d0.y + x0.z*w2d0.z + x0.w*w2d0.w
                 + x1.x*w2d1.x + x1.y*w2d1.y + x1.z*w2d1.z + x1.w*w2d1.w;
        float d3 = x0.x*w3d0.x + x0.y*w3d0.y + x0.z*w3d0.z + x0.w*w3d0.w
                 + x1.x*w3d1.x + x1.y*w3d1.y + x1.z*w3d1.z + x1.w*w3d1.w;
#pragma unroll
        for (int m = 1; m < 16; m <<= 1) {
            s1 += __shfl_xor(s1, m);
            s2 += __shfl_xor(s2, m);
            s3 += __shfl_xor(s3, m);
            d1 += __shfl_xor(d1, m);
            d2 += __shfl_xor(d2, m);
            d3 += __shfl_xor(d3, m);
        }
        if (l == 0) {
            *(float4*)(proj + (size_t)n * 8)     = make_float4(s1, s2, s3, 0.f);
            *(float4*)(proj + (size_t)n * 8 + 4) = make_float4(d1, d2, d3, 0.f);
        }
        return;
    }
    bid -= nbProj;
    {
        int w = bid, NW = NWPART;
        for (int i = tid; i < nbkt; i += 256) lh[i] = 0;
        __syncthreads();
        int per = (E + NW - 1) / NW;
        int e0 = w * per, e1 = min(E, e0 + per);
        for (int e = e0 + tid; e < e1; e += 256)
            atomicAdd(&lh[dst[e] >> 6], 1);
        __syncthreads();
        for (int b = tid; b < nbkt; b += 256)
            hist[b * NW + w] = lh[b];
    }
}

// ---------------- partition scan, parallelized
__global__ __launch_bounds__(NWPART) void k_pscan_a(int* __restrict__ hist,
                                                    int* __restrict__ tot)
{
    __shared__ int s[NWPART];
    int b = blockIdx.x, t = threadIdx.x;
    int v = hist[b * NWPART + t];
    s[t] = v;
    __syncthreads();
    for (int d = 1; d < NWPART; d <<= 1) {
        int u = (t >= d) ? s[t - d] : 0;
        __syncthreads();
        s[t] += u;
        __syncthreads();
    }
    hist[b * NWPART + t] = s[t] - v;
    if (t == NWPART - 1) tot[b] = s[NWPART - 1];
}

__global__ __launch_bounds__(MAXBKT) void k_pscan_b(const int* __restrict__ tot,
                                                    int* __restrict__ bbase,
                                                    int E, int nbkt)
{
    __shared__ int s[MAXBKT];
    int b = threadIdx.x;
    int v = (b < nbkt) ? tot[b] : 0;
    s[b] = v;
    __syncthreads();
    for (int d = 1; d < MAXBKT; d <<= 1) {
        int u = (b >= d) ? s[b - d] : 0;
        __syncthreads();
        s[b] += u;
        __syncthreads();
    }
    if (b < nbkt) bbase[b] = s[b] - v;
    if (b == nbkt - 1) bbase[nbkt] = E;
}

// ======== single-plane bf16 GEMM helpers (BM=64, 8 waves = 2rw x 4cw) ========

__device__ inline void g_pass_global(const unsigned short* __restrict__ A, int N, int row0,
                                     int ln, int g, int lane, int cw,
                                     const unsigned short* __restrict__ wf, f4v acc[2][2])
{
#pragma unroll
    for (int ks = 0; ks < 4; ++ks) {
        s8v a[2];
#pragma unroll
        for (int fr = 0; fr < 2; ++fr) {
            int rA = min(row0 + fr * 16 + ln, N - 1);
            a[fr] = *(const s8v*)(A + (size_t)rA * 128 + ks * 32 + g * 8);
        }
#pragma unroll
        for (int ct2 = 0; ct2 < 2; ++ct2) {
            int ct = cw * 2 + ct2;
            s8v wv = *(const s8v*)(wf + ((((ct << 2) + ks) * 64) + lane) * 8);
#pragma unroll
            for (int fr = 0; fr < 2; ++fr)
                acc[fr][ct2] = __builtin_amdgcn_mfma_f32_16x16x32_bf16(a[fr], wv, acc[fr][ct2], 0, 0, 0);
        }
    }
}

__device__ inline void g_pass_lds(const unsigned short* __restrict__ act,
                                  int rw, int ln, int g, int lane, int cw,
                                  const unsigned short* __restrict__ wf, f4v acc[2][2])
{
#pragma unroll
    for (int ks = 0; ks < 4; ++ks) {
        s8v a[2];
#pragma unroll
        for (int fr = 0; fr < 2; ++fr) {
            int rl = rw * 32 + fr * 16 + ln;
            a[fr] = *(const s8v*)(&act[(rl * 128 + ks * 32 + g * 8) ^ ((ln & 7) << 3)]);
        }
#pragma unroll
        for (int ct2 = 0; ct2 < 2; ++ct2) {
            int ct = cw * 2 + ct2;
            s8v wv = *(const s8v*)(wf + ((((ct << 2) + ks) * 64) + lane) * 8);
#pragma unroll
            for (int fr = 0; fr < 2; ++fr)
                acc[fr][ct2] = __builtin_amdgcn_mfma_f32_16x16x32_bf16(a[fr], wv, acc[fr][ct2], 0, 0, 0);
        }
    }
}

__device__ inline void write_act(f4v acc[2][2], const float* __restrict__ bias,
                                 unsigned short* __restrict__ act,
                                 int rw, int cw, int ln, int g)
{
#pragma unroll
    for (int ct2 = 0; ct2 < 2; ++ct2) {
        int col = (cw * 2 + ct2) * 16 + ln;
        float bv = bias[col];
#pragma unroll
        for (int fr = 0; fr < 2; ++fr) {
#pragma unroll
            for (int q = 0; q < 4; ++q) {
                int rl = rw * 32 + fr * 16 + g * 4 + q;
                float o = fmaxf(acc[fr][ct2][q] + bv, 0.f);
                act[(rl * 128 + col) ^ ((rl & 7) << 3)] = f2bf_rne(o);
                acc[fr][ct2][q] = 0.f;
            }
        }
    }
}

// ================= K4: fused part2 scatter + 3-layer message MLP (fp8 msg out)
__global__ __launch_bounds__(512) void k_mid(const int* __restrict__ src,
                                             const int* __restrict__ dst,
                                             const int* __restrict__ hist,
                                             const int* __restrict__ bbase,
                                             unsigned* __restrict__ ebuf,
                                             int E, int nbkt,
                                             const unsigned short* __restrict__ hb,
                                             const unsigned short* __restrict__ w1,
                                             const unsigned short* __restrict__ w2,
                                             const unsigned short* __restrict__ w3,
                                             const float* __restrict__ b1,
                                             const float* __restrict__ b2,
                                             const float* __restrict__ b3,
                                             unsigned char* __restrict__ msg, int N)
{
    __shared__ int cur[MAXBKT];
    __shared__ unsigned short act0[8192];
    __shared__ unsigned short act1[8192];
    int tid = threadIdx.x;

    if (blockIdx.x < NWPART) {
        int w = blockIdx.x, NW = NWPART;
        for (int i = tid; i < nbkt; i += 512)
            cur[i] = hist[i * NW + w] + bbase[i];
        __syncthreads();
        int per = (E + NW - 1) / NW;
        int e0 = w * per, e1 = min(E, e0 + per);
        for (int e = e0 + tid; e < e1; e += 512) {
            int d = dst[e], b = d >> 6;
            int pos = atomicAdd(&cur[b], 1);
            ebuf[pos] = ((unsigned)src[e] << 7) | (unsigned)(d & 63);
        }
        return;
    }
    int mb   = blockIdx.x - NWPART;
    int lane = tid & 63;
    int wid  = tid >> 6;
    int rw   = wid >> 2;
    int cw   = wid & 3;
    int ln   = lane & 15;
    int g    = lane >> 4;
    int row0 = mb * 64 + rw * 32;

    f4v acc[2][2] = {};
    g_pass_global(hb, N, row0, ln, g, lane, cw, w1, acc);
    write_act(acc, b1, act0, rw, cw, ln, g);
    __syncthreads();
    g_pass_lds(act0, rw, ln, g, lane, cw, w2, acc);
    write_act(acc, b2, act1, rw, cw, ln, g);
    __syncthreads();
    g_pass_lds(act1, rw, ln, g, lane, cw, w3, acc);
    write_act(acc, b3, act0, rw, cw, ln, g);
    __syncthreads();
    // coalesced fp8 copyout
#pragma unroll
    for (int i = 0; i < 2; ++i) {
        int id  = tid + 512 * i;
        int row = id >> 4;
        int c8  = (id & 15) * 8;
        int grow = mb * 64 + row;
        if (grow < N) {
            s8v v = *(const s8v*)(&act0[(row * 128 + c8) ^ ((row & 7) << 3)]);
            unsigned long long packed = 0;
#pragma unroll
            for (int k = 0; k < 8; ++k)
                packed |= (unsigned long long)fp8e(bf2f((unsigned short)v[k])) << (8 * k);
            *(unsigned long long*)(msg + (size_t)grow * 128 + c8) = packed;
        }
    }
}

// ================= K5: fused local-CSR + aggregation (fp8, 2-deep) + head ======
__global__ __launch_bounds__(512) void k_tail(const unsigned short* __restrict__ hb,
                                              const unsigned char* __restrict__ msgb,
                                              const float* __restrict__ proj,
                                              const int* __restrict__ bbase,
                                              const unsigned* __restrict__ ebuf,
                                              const float* __restrict__ ba1,
                                              const float* __restrict__ ba2,
                                              const float* __restrict__ ba3,
                                              const unsigned short* __restrict__ wc1a,
                                              const unsigned short* __restrict__ wc1b,
                                              const unsigned short* __restrict__ wc2,
                                              const float* __restrict__ bc1,
                                              const float* __restrict__ bc2,
                                              float* __restrict__ out, int N)
{
    __shared__ unsigned short hn[8192];
    __shared__ unsigned short act0[8192];
    __shared__ int lperm[1536];
    __shared__ int lcnt[64];
    __shared__ int lsc[64];
    __shared__ int loffs[65];
    __shared__ int lcur[64];
    int tid  = threadIdx.x;
    int lane = tid & 63;
    int l    = lane & 15;
    int grp  = lane >> 4;      // 0..3 within wave
    int wv   = tid >> 6;       // 0..7
    int r0   = blockIdx.x * 64;
    float b1 = ba1[0], b2 = ba2[0], b3 = ba3[0];

    // ---- prologue: local CSR for this bucket (64 dst nodes)
    int be0 = bbase[blockIdx.x], be1 = bbase[blockIdx.x + 1];
    if (tid < 64) lcnt[tid] = 0;
    __syncthreads();
    for (int e = be0 + tid; e < be1; e += 512)
        atomicAdd(&lcnt[ebuf[e] & 63], 1);
    __syncthreads();
    if (tid < 64) lsc[tid] = lcnt[tid];
    __syncthreads();
    for (int d = 1; d < 64; d <<= 1) {
        int u = (tid < 64 && tid >= d) ? lsc[tid - d] : 0;
        __syncthreads();
        if (tid < 64) lsc[tid] += u;
        __syncthreads();
    }
    if (tid < 64) {
        int excl = lsc[tid] - lcnt[tid];
        loffs[tid] = excl;
        lcur[tid]  = excl;
        if (tid == 63) loffs[64] = lsc[63];
    }
    __syncthreads();
    for (int e = be0 + tid; e < be1; e += 512) {
        unsigned r = ebuf[e];
        int p = atomicAdd(&lcur[r & 63], 1);
        if (p < 1536) lperm[p] = (int)(r >> 7);
    }
    __syncthreads();

    // ---- Phase A: aggregation into hn LDS (fp8 rows, 2-deep unrolled gather)
    for (int rnd = 0; rnd < 2; ++rnd) {
        int rl = rnd * 32 + wv * 4 + grp;
        int n  = r0 + rl;
        bool alive = (n < N);
        int o0 = loffs[rl], o1 = loffs[rl + 1];
        float dd1 = 0.f, dd2 = 0.f, dd3 = 0.f;
        if (alive) {
            dd1 = proj[(size_t)n * 8 + 4];
            dd2 = proj[(size_t)n * 8 + 5];
            dd3 = proj[(size_t)n * 8 + 6];
        }
        int deg = o1 - o0;

        int   m0 = min(deg, 16);
        int   sc = 0;
        float a1c = 0.f, a2c = 0.f, a3c = 0.f;
        if (l < m0) {
            sc = lperm[o0 + l];
            float4 sp = *(const float4*)(proj + (size_t)sc * 8);
            a1c = __expf(fmaxf(sp.x + dd1 + b1, 0.f));
            a2c = __expf(fmaxf(sp.y + dd2 + b2, 0.f));
            a3c = __expf(fmaxf(sp.z + dd3 + b3, 0.f));
        }
        float s1 = a1c, s2 = a2c, s3 = a3c;
        for (int i = o0 + 16 + l; i < o1; i += 16) {
            int s = lperm[i];
            float4 sp = *(const float4*)(proj + (size_t)s * 8);
            s1 += __expf(fmaxf(sp.x + dd1 + b1, 0.f));
            s2 += __expf(fmaxf(sp.y + dd2 + b2, 0.f));
            s3 += __expf(fmaxf(sp.z + dd3 + b3, 0.f));
        }
#pragma unroll
        for (int m = 1; m < 16; m <<= 1) {
            s1 += __shfl_xor(s1, m);
            s2 += __shfl_xor(s2, m);
            s3 += __shfl_xor(s3, m);
        }
        float r1 = 1.f / s1, r2 = 1.f / s2, r3 = 1.f / s3;

        float acc[8] = {};
        int gbase = grp << 4;
        {
            float wvv = (a1c * r1 + a2c * r2 + a3c * r3) * (1.f / 3.f);
            int j = 0;
            for (; j + 2 <= m0; j += 2) {
                int   sA = __shfl(sc, gbase + j);
                int   sB = __shfl(sc, gbase + j + 1);
                float wA = __shfl(wvv, gbase + j);
                float wB = __shfl(wvv, gbase + j + 1);
                unsigned long long rA = *(const unsigned long long*)(msgb + (size_t)sA * 128 + l * 8);
                unsigned long long rB = *(const unsigned long long*)(msgb + (size_t)sB * 128 + l * 8);
#pragma unroll
                for (int k = 0; k < 8; ++k) acc[k] += wA * fp8d((unsigned)(rA >> (8 * k)));
#pragma unroll
                for (int k = 0; k < 8; ++k) acc[k] += wB * fp8d((unsigned)(rB >> (8 * k)));
            }
            if (j < m0) {
                int   s = __shfl(sc, gbase + j);
                float w = __shfl(wvv, gbase + j);
                unsigned long long raw = *(const unsigned long long*)(msgb + (size_t)s * 128 + l * 8);
#pragma unroll
                for (int k = 0; k < 8; ++k) acc[k] += w * fp8d((unsigned)(raw >> (8 * k)));
            }
        }
        for (int base = o0 + 16; base < o1; base += 16) {
            int m  = min(16, o1 - base);
            int sv = 0;
            float wvv = 0.f;
            if (l < m) {
                sv = lperm[base + l];
                float4 sp = *(const float4*)(proj + (size_t)sv * 8);
                float a1 = __expf(fmaxf(sp.x + dd1 + b1, 0.f));
                float a2 = __expf(fmaxf(sp.y + dd2 + b2, 0.f));
                float a3 = __expf(fmaxf(sp.z + dd3 + b3, 0.f));
                wvv = (a1 * r1 + a2 * r2 + a3 * r3) * (1.f / 3.f);
            }
            int j = 0;
            for (; j + 2 <= m; j += 2) {
                int   sA = __shfl(sv, gbase + j);
                int   sB = __shfl(sv, gbase + j + 1);
                float wA = __shfl(wvv, gbase + j);
                float wB = __shfl(wvv, gbase + j + 1);
                unsigned long long rA = *(const unsigned long long*)(msgb + (size_t)sA * 128 + l * 8);
                unsigned long long rB = *(const unsigned long long*)(msgb + (size_t)sB * 128 + l * 8);
#pragma unroll
                for (int k = 0; k < 8; ++k) acc[k] += wA * fp8d((unsigned)(rA >> (8 * k)));
#pragma unroll
                for (int k = 0; k < 8; ++k) acc[k] += wB * fp8d((unsigned)(rB >> (8 * k)));
            }
            if (j < m) {
                int   s = __shfl(sv, gbase + j);
                float w = __shfl(wvv, gbase + j);
                unsigned long long raw = *(const unsigned long long*)(msgb + (size_t)s * 128 + l * 8);
#pragma unroll
                for (int k = 0; k < 8; ++k) acc[k] += w * fp8d((unsigned)(raw >> (8 * k)));
            }
        }
        float inv = (alive && deg > 0) ? 1.f / (float)deg : 0.f;
        s8v hv;
#pragma unroll
        for (int k = 0; k < 8; ++k)
            hv[k] = (short)f2bf_rne(acc[k] * inv);
        *(s8v*)(&hn[(rl * 128 + l * 8) ^ ((rl & 7) << 3)]) = hv;
    }
    __syncthreads();

    // ---- Phase B: c1 (hb global + hn LDS) -> act0 -> c2 -> out
    int wid  = tid >> 6;
    int rw   = wid >> 2;
    int cw   = wid & 3;
    int ln   = lane & 15;
    int g    = lane >> 4;
    int row0 = r0 + rw * 32;

    f4v acc2[2][2] = {};
    g_pass_global(hb, N, row0, ln, g, lane, cw, wc1a, acc2);
    g_pass_lds(hn, rw, ln, g, lane, cw, wc1b, acc2);
    write_act(acc2, bc1, act0, rw, cw, ln, g);
    __syncthreads();
    g_pass_lds(act0, rw, ln, g, lane, cw, wc2, acc2);
#pragma unroll
    for (int ct2 = 0; ct2 < 2; ++ct2) {
        int col = (cw * 2 + ct2) * 16 + ln;
        float bv = bc2[col];
#pragma unroll
        for (int fr = 0; fr < 2; ++fr) {
#pragma unroll
            for (int q = 0; q < 4; ++q) {
                int orow = row0 + fr * 16 + g * 4 + q;
                if (orow < N)
                    out[(size_t)orow * 128 + col] = acc2[fr][ct2][q] + bv;
            }
        }
    }
}

extern "C" void kernel_launch(void* const* d_in, const int* in_sizes, int n_in,
                              void* d_out, int out_size, void* d_ws, size_t ws_size,
                              hipStream_t stream)
{
    const float* h   = (const float*)d_in[0];
    const int*   src = (const int*)d_in[1];
    const int*   dst = (const int*)d_in[2];
    const float* Wm1 = (const float*)d_in[3];
    const float* bm1 = (const float*)d_in[4];
    const float* Wm2 = (const float*)d_in[5];
    const float* bm2 = (const float*)d_in[6];
    const float* Wm3 = (const float*)d_in[7];
    const float* bm3 = (const float*)d_in[8];
    const float* Wa1 = (const float*)d_in[9];
    const float* ba1 = (const float*)d_in[10];
    const float* Wa2 = (const float*)d_in[11];
    const float* ba2 = (const float*)d_in[12];
    const float* Wa3 = (const float*)d_in[13];
    const float* ba3 = (const float*)d_in[14];
    const float* Wc1 = (const float*)d_in[15];
    const float* bc1 = (const float*)d_in[16];
    const float* Wc2 = (const float*)d_in[17];
    const float* bc2 = (const float*)d_in[18];

    const int N = in_sizes[0] / NDIM;
    const int E = in_sizes[1];
    const int nbkt = (N + 63) >> 6;            // 64-node buckets == k_tail tiles
    float* out = (float*)d_out;

    // workspace layout
    unsigned short* wt  = (unsigned short*)d_ws;                 // 6*16384 ushorts (192 KB)
    unsigned short* hb  = wt + 6 * 16384;                        // N*128 bf16 (h cast)
    unsigned char* mb2  = (unsigned char*)(hb + (size_t)N * NDIM); // N*128 fp8 (msg)
    float* proj = (float*)(mb2 + (size_t)N * NDIM);              // N*8
    int* hist   = (int*)(proj + (size_t)N * 8);                  // nbkt*NWPART
    int* bbase  = hist + MAXBKT * NWPART;                        // nbkt+1
    int* btot   = bbase + MAXBKT + 1;                            // nbkt
    unsigned* ebuf = (unsigned*)(btot + MAXBKT);                 // E

    const unsigned short* wt_m1  = wt;
    const unsigned short* wt_m2  = wt + 1 * 16384;
    const unsigned short* wt_m3  = wt + 2 * 16384;
    const unsigned short* wt_c1a = wt + 3 * 16384;
    const unsigned short* wt_c1b = wt + 4 * 16384;
    const unsigned short* wt_c2  = wt + 5 * 16384;

    int nbProj = (N + 15) / 16;
    int gb64   = nbkt;

    // K1: cvt_w (384) + proj (nbProj) + part1 (NWPART)
    k_front<<<384 + nbProj + NWPART, 256, 0, stream>>>(
        h, Wa1, Wa2, Wa3, proj, hb,
        Wm1, Wm2, Wm3, Wc1, Wc1 + 128 * 128, Wc2, wt,
        dst, hist, N, E, nbkt);

    // K2/K3: partition scans
    k_pscan_a<<<nbkt, NWPART, 0, stream>>>(hist, btot);
    k_pscan_b<<<1, MAXBKT, 0, stream>>>(btot, bbase, E, nbkt);

    // K4: part2 (NWPART) + mlp3 (gb64), fp8 msg out
    k_mid<<<NWPART + gb64, 512, 0, stream>>>(
        src, dst, hist, bbase, ebuf, E, nbkt,
        hb, wt_m1, wt_m2, wt_m3, bm1, bm2, bm3, mb2, N);

    // K5: fused local-CSR + fp8-gather aggregation + head
    k_tail<<<gb64, 512, 0, stream>>>(
        hb, mb2, proj, bbase, ebuf, ba1, ba2, ba3,
        wt_c1a, wt_c1b, wt_c2, bc1, bc2, out, N);
}